// Round 1
// baseline (527.490 us; speedup 1.0000x reference)
//
#include <hip/hip_runtime.h>

// NeighborCooccurrenceEncoder: B=4096, L=256, FEAT=64.
// out[0 .. B*L*64)            = src_feats: ch0 = (src_ids[b,j] in dst row b) * scale, rest 0
// out[B*L*64 .. 2*B*L*64)     = dst_feats: ch0 = (dst_ids[b,j] in src row b) * scale, rest 0

#define BATCH 4096
#define LSEQ 256
#define FEAT 64
#define MAXID 10000
#define NWORDS 313  // ceil(10000/32)

__global__ __launch_bounds__(256) void cooc_kernel(
    const int* __restrict__ src_ids,
    const int* __restrict__ dst_ids,
    const float* __restrict__ scale,
    float* __restrict__ out)
{
    __shared__ int s_src[LSEQ];
    __shared__ int s_dst[LSEQ];
    __shared__ unsigned int bs_src[NWORDS];
    __shared__ unsigned int bs_dst[NWORDS];
    __shared__ float f_src[LSEQ];
    __shared__ float f_dst[LSEQ];

    const int b = blockIdx.x;
    const int t = threadIdx.x;

    // zero the bitsets
    for (int i = t; i < NWORDS; i += 256) { bs_src[i] = 0u; bs_dst[i] = 0u; }
    __syncthreads();

    const int sv = src_ids[(size_t)b * LSEQ + t];
    const int dv = dst_ids[(size_t)b * LSEQ + t];
    s_src[t] = sv;
    s_dst[t] = dv;
    if ((unsigned)sv < (unsigned)MAXID)
        atomicOr(&bs_src[sv >> 5], 1u << (sv & 31));
    if ((unsigned)dv < (unsigned)MAXID)
        atomicOr(&bs_dst[dv >> 5], 1u << (dv & 31));
    __syncthreads();

    const float s = scale[0];

    // membership tests (bitset fast path; linear-scan fallback for safety)
    bool src_in_dst;
    if ((unsigned)sv < (unsigned)MAXID) {
        src_in_dst = (bs_dst[sv >> 5] >> (sv & 31)) & 1u;
    } else {
        src_in_dst = false;
        for (int k = 0; k < LSEQ; ++k) src_in_dst |= (s_dst[k] == sv);
    }
    bool dst_in_src;
    if ((unsigned)dv < (unsigned)MAXID) {
        dst_in_src = (bs_src[dv >> 5] >> (dv & 31)) & 1u;
    } else {
        dst_in_src = false;
        for (int k = 0; k < LSEQ; ++k) dst_in_src |= (s_src[k] == dv);
    }

    f_src[t] = src_in_dst ? s : 0.0f;
    f_dst[t] = dst_in_src ? s : 0.0f;
    __syncthreads();

    // Coalesced float4 writes of the two 64KiB output slabs for this row.
    float* osrc = out + (size_t)b * LSEQ * FEAT;
    float* odst = out + (size_t)BATCH * LSEQ * FEAT + (size_t)b * LSEQ * FEAT;
    // LSEQ*FEAT = 16384 floats = 4096 float4; 256 threads -> 16 float4 each.
#pragma unroll
    for (int k = 0; k < 16; ++k) {
        const int o4 = k * 256 + t;   // float4 index within slab
        const int fo = o4 * 4;        // float offset
        const int j  = fo >> 6;       // sequence position
        const int c  = fo & 63;       // channel of .x component
        float4 v = make_float4((c == 0) ? f_src[j] : 0.0f, 0.0f, 0.0f, 0.0f);
        float4 w = make_float4((c == 0) ? f_dst[j] : 0.0f, 0.0f, 0.0f, 0.0f);
        reinterpret_cast<float4*>(osrc)[o4] = v;
        reinterpret_cast<float4*>(odst)[o4] = w;
    }
}

extern "C" void kernel_launch(void* const* d_in, const int* in_sizes, int n_in,
                              void* d_out, int out_size, void* d_ws, size_t ws_size,
                              hipStream_t stream) {
    const int*   src_ids = (const int*)d_in[0];
    const int*   dst_ids = (const int*)d_in[1];
    const float* scale   = (const float*)d_in[2];
    float*       out     = (float*)d_out;

    cooc_kernel<<<BATCH, 256, 0, stream>>>(src_ids, dst_ids, scale, out);
}